// Round 12
// baseline (225.181 us; speedup 1.0000x reference)
//
#include <hip/hip_runtime.h>
#include <hip/hip_bf16.h>

typedef short bf4 __attribute__((ext_vector_type(4)));
typedef short short8 __attribute__((ext_vector_type(8)));
typedef float f32x4 __attribute__((ext_vector_type(4)));

#define MFMA(a, b, c) __builtin_amdgcn_mfma_f32_16x16x32_bf16((a), (b), (c), 0, 0, 0)

#define NB 2
#define NS 1024
#define NHID 768
#define NHEAD 12
#define NDH 64

__device__ __forceinline__ short f2bf(float x) {
    __hip_bfloat16 h = __float2bfloat16(x);
    return *reinterpret_cast<short*>(&h);
}

// bijective XCD swizzle (requires nwg % 8 == 0): consecutive output ids
// land on ONE XCD in chunks of nwg/8.
__device__ __forceinline__ int xcd_swz(int orig, int nwg) {
    return (orig & 7) * (nwg >> 3) + (orig >> 3);
}

typedef const __attribute__((address_space(1))) void gas_t;
typedef __attribute__((address_space(3))) void las_t;
__device__ __forceinline__ void gld_lds16(const float* g, float* l) {
    __builtin_amdgcn_global_load_lds((gas_t*)g, (las_t*)l, 16, 0, 0);
}
__device__ __forceinline__ void gld_lds16s(const short* g, short* l) {
    __builtin_amdgcn_global_load_lds((gas_t*)g, (las_t*)l, 16, 0, 0);
}

// ---------------------------------------------------------------------------
// Kernel 0: convert hidden + Wq/Wk/Wv to bf16 (once).
// ---------------------------------------------------------------------------
#define NHE (2048 * 768)
#define WE  (768 * 768)
__global__ void cvt_bf16_all(
    const float* __restrict__ hidden,
    const float* __restrict__ Wq, const float* __restrict__ Wk,
    const float* __restrict__ Wv,
    short* __restrict__ Xbf, short* __restrict__ Wbf)
{
    const int base = (blockIdx.x * 256 + threadIdx.x) * 4;
    const float* src; short* dst; int off;
    if (base < NHE)               { src = hidden; dst = Xbf;          off = base; }
    else if (base < NHE + WE)     { src = Wq;     dst = Wbf;          off = base - NHE; }
    else if (base < NHE + 2 * WE) { src = Wk;     dst = Wbf + WE;     off = base - NHE - WE; }
    else                          { src = Wv;     dst = Wbf + 2 * WE; off = base - NHE - 2 * WE; }
    f32x4 v = *reinterpret_cast<const f32x4*>(src + off);
    bf4 r;
    r[0] = f2bf(v[0]); r[1] = f2bf(v[1]); r[2] = f2bf(v[2]); r[3] = f2bf(v[3]);
    *reinterpret_cast<bf4*>(dst + off) = r;
}

// ---------------------------------------------------------------------------
// Kernel 1: QKV GEMM, LDS-staged; 1D grid 576 + XCD swizzle (72 blocks/XCD
// = 2 full m-panels -> A panel stays in that XCD's L2).
// ---------------------------------------------------------------------------
__global__ __launch_bounds__(256, 3) void qkv_gemm(
    const short* __restrict__ Xbf, const short* __restrict__ Wbf,
    const float* __restrict__ bq, const float* __restrict__ bk,
    const float* __restrict__ bv,
    short* __restrict__ Qo, short* __restrict__ Ko, short* __restrict__ VTo)
{
    const int lane = threadIdx.x & 63;
    const int wave = threadIdx.x >> 6;
    const int lg = lane >> 4, lr = lane & 15;

    const int wgid = xcd_swz(blockIdx.x, 16 * 36);
    const int m0 = (wgid / 36) * 128;
    const int n0 = (wgid % 36) * 64;
    const int proj = n0 / NHID;
    const int ncol0 = n0 % NHID;
    const float* bias = proj == 0 ? bq : (proj == 1 ? bk : bv);

    __shared__ short Alds[2][128 * 64];
    __shared__ short Blds[2][64 * 64];

    f32x4 acc[2][4];
    #pragma unroll
    for (int mm = 0; mm < 2; ++mm)
        #pragma unroll
        for (int s = 0; s < 4; ++s) acc[mm][s] = (f32x4){0.f, 0.f, 0.f, 0.f};

    auto stage = [&](int t, int buf) {
        const int k0 = t * 64;
        #pragma unroll
        for (int p = 0; p < 4; ++p) {
            const int op = wave * 4 + p;
            const int unit = op * 64 + lane;
            const int r = unit >> 3, u = unit & 7;
            const int g = u ^ (r & 7);
            gld_lds16s(Xbf + (size_t)(m0 + r) * NHID + k0 + g * 8,
                       &Alds[buf][op * 512]);
        }
        #pragma unroll
        for (int p = 0; p < 2; ++p) {
            const int op = wave * 2 + p;
            const int unit = op * 64 + lane;
            const int r = unit >> 3, u = unit & 7;
            const int g = u ^ (r & 7);
            gld_lds16s(Wbf + (size_t)(n0 + r) * NHID + k0 + g * 8,
                       &Blds[buf][op * 512]);
        }
    };

    auto compute = [&](int buf) {
        #pragma unroll
        for (int kk = 0; kk < 2; ++kk) {
            const int U = kk * 4 + lg;
            short8 a[2];
            #pragma unroll
            for (int mm = 0; mm < 2; ++mm) {
                const int R = wave * 32 + mm * 16 + lr;
                a[mm] = *reinterpret_cast<const short8*>(
                    &Alds[buf][(R * 8 + (U ^ (R & 7))) * 8]);
            }
            #pragma unroll
            for (int s = 0; s < 4; ++s) {
                const int R = s * 16 + lr;
                short8 b = *reinterpret_cast<const short8*>(
                    &Blds[buf][(R * 8 + (U ^ (R & 7))) * 8]);
                acc[0][s] = MFMA(a[0], b, acc[0][s]);
                acc[1][s] = MFMA(a[1], b, acc[1][s]);
            }
        }
    };

    stage(0, 0);
    #pragma unroll 2
    for (int t = 0; t < 12; ++t) {
        const int buf = t & 1;
        asm volatile("s_waitcnt vmcnt(0)" ::: "memory");
        __syncthreads();
        if (t < 11) stage(t + 1, buf ^ 1);
        compute(buf);
    }

    #pragma unroll
    for (int mm = 0; mm < 2; ++mm) {
        #pragma unroll
        for (int s = 0; s < 4; ++s) {
            const int ncol = ncol0 + s * 16 + lr;
            const float badd = bias[ncol];
            #pragma unroll
            for (int r = 0; r < 4; ++r) {
                const int m = m0 + wave * 32 + mm * 16 + lg * 4 + r;
                const short v16 = f2bf(acc[mm][s][r] + badd);
                if (proj == 0) {
                    Qo[(size_t)m * NHID + ncol] = v16;
                } else if (proj == 1) {
                    Ko[(size_t)m * NHID + ncol] = v16;
                } else {
                    const int b = m >> 10, ss = m & 1023;
                    const int h = ncol >> 6, dd = ncol & 63;
                    VTo[(((size_t)(b * NHEAD + h) * NDH + dd) << 10) + ss] = v16;
                }
            }
        }
    }
}

// ---------------------------------------------------------------------------
// Kernel 2: bias GEMM -> bf16, pre-scaled + mask folded (unchanged; at its
// fetch roofline).
// ---------------------------------------------------------------------------
__global__ __launch_bounds__(256, 2) void bias_gemm(
    const short* __restrict__ Q,
    const float* __restrict__ bbox,
    const float* __restrict__ mask,
    short* __restrict__ biasH)        // (2,12,1024,1024) bf16
{
    const int lane = threadIdx.x & 63;
    const int wave = threadIdx.x >> 6;
    const int lg = lane >> 4, lr = lane & 15;
    const int i = blockIdx.x;
    const int jq = wave * 256;

    __shared__ float lds[4][2][2048];

    short8 qa[2][2];
    #pragma unroll
    for (int b2 = 0; b2 < 2; ++b2)
        #pragma unroll
        for (int kk = 0; kk < 2; ++kk)
            qa[b2][kk] = *reinterpret_cast<const short8*>(
                Q + ((size_t)(b2 * NS) + i) * NHID + lr * 64 + kk * 32 + lg * 8);

    const int r_half = lane >> 5;
    const int u_lin = lane & 31;

    auto stage = [&](int t, int buf) {
        const int j0 = jq + t * 16;
        float* dst = &lds[wave][buf][0];
        #pragma unroll
        for (int w = 0; w < 8; ++w) {
            const int r = 2 * w + r_half;
            const int u = u_lin ^ (r & 7);
            const float* src = bbox + (size_t)(i * NS + j0 + r) * 128 + u * 4;
            gld_lds16(src, dst + w * 256);
        }
    };

    auto compute = [&](int t, int buf) {
        const float* tile = &lds[wave][buf][0];
        const int j0 = jq + t * 16;
        const int x = lr & 7;
        #pragma unroll
        for (int b2 = 0; b2 < 2; ++b2) {
            const float mk = mask[b2 * NS + j0 + lr];
            f32x4 c = (f32x4){0.f, 0.f, 0.f, 0.f};
            #pragma unroll
            for (int kk = 0; kk < 2; ++kk) {
                const int q0 = b2 * 16 + kk * 8 + lg * 2;
                f32x4 ca = *reinterpret_cast<const f32x4*>(tile + (size_t)(lr * 32 + ((q0)     ^ x)) * 4);
                f32x4 cb = *reinterpret_cast<const f32x4*>(tile + (size_t)(lr * 32 + ((q0 + 1) ^ x)) * 4);
                short8 bf;
                bf[0] = f2bf(ca[0]); bf[1] = f2bf(ca[1]); bf[2] = f2bf(ca[2]); bf[3] = f2bf(ca[3]);
                bf[4] = f2bf(cb[0]); bf[5] = f2bf(cb[1]); bf[6] = f2bf(cb[2]); bf[7] = f2bf(cb[3]);
                c = MFMA(qa[b2][kk], bf, c);
            }
            if (lg < 3) {
                #pragma unroll
                for (int r = 0; r < 4; ++r) {
                    const int n = lg * 4 + r;
                    biasH[((size_t)(b2 * NHEAD + n) * NS + i) * NS + j0 + lr] =
                        f2bf(c[r] * 0.125f + mk);
                }
            }
        }
    };

    stage(0, 0);
    for (int t = 0; t < 16; ++t) {
        const int buf = t & 1;
        asm volatile("s_waitcnt lgkmcnt(0)" ::: "memory");
        if (t < 15) stage(t + 1, buf ^ 1);
        if (t == 0 || t == 15) asm volatile("s_waitcnt vmcnt(8)"  ::: "memory");
        else                   asm volatile("s_waitcnt vmcnt(16)" ::: "memory");
        compute(t, buf);
    }
}

// ---------------------------------------------------------------------------
// Kernel 3: attention. XCD-swizzled 1D grid (192 blocks/XCD = 3 full (b,h)
// groups -> K/V L2-local). K/V reg-dbuf (1-deep), bias reg prefetch 2-deep
// (3-name rotation, unrolled), bias through single-buffer per-wave LDS.
// ---------------------------------------------------------------------------
__global__ __launch_bounds__(256, 3) void attn2(
    const short* __restrict__ Q,
    const short* __restrict__ K,
    const short* __restrict__ VT,
    const short* __restrict__ biasH,
    float* __restrict__ out)
{
    const int lane = threadIdx.x & 63;
    const int wave = threadIdx.x >> 6;
    const int lg = lane >> 4, lr = lane & 15;

    const int wgid = xcd_swz(blockIdx.x, 24 * 64);
    const int bh = wgid / 64;             // (b,h) group contiguous per XCD
    const int i0 = (wgid % 64) * 16;
    const int b = bh / NHEAD, h = bh % NHEAD;
    const int jq = wave * 256;

    __shared__ short plds[4][16][40];
    __shared__ short blds[4][16 * 40];
    __shared__ float numlds[4][16][68];
    __shared__ float denlds[4][16];

    short8 qa[2];
    #pragma unroll
    for (int kk = 0; kk < 2; ++kk)
        qa[kk] = *reinterpret_cast<const short8*>(
            Q + ((size_t)(b * NS) + i0 + lr) * NHID + h * 64 + kk * 32 + lg * 8);

    const short* Kb = K + (size_t)b * NS * NHID + h * 64;
    const short* Vb = VT + (size_t)(b * NHEAD + h) * NDH * NS;
    const short* Bb = biasH + ((size_t)(b * NHEAD + h) * NS + i0) * NS;

    f32x4 ctx[4];
    #pragma unroll
    for (int dt = 0; dt < 4; ++dt) ctx[dt] = (f32x4){0.f, 0.f, 0.f, 0.f};
    f32x4 den = (f32x4){0.f, 0.f, 0.f, 0.f};

    short8 kfA[4], vfA[4];
    short8 kfB[4], vfB[4];
    short8 bv0, bv1, bv2;

    auto kvload = [&](int t, short8* kf, short8* vf) {
        const int j0 = jq + t * 32;
        #pragma unroll
        for (int s = 0; s < 2; ++s)
            #pragma unroll
            for (int kk = 0; kk < 2; ++kk)
                kf[s * 2 + kk] = *reinterpret_cast<const short8*>(
                    Kb + (size_t)(j0 + s * 16 + lr) * NHID + kk * 32 + lg * 8);
        #pragma unroll
        for (int dt = 0; dt < 4; ++dt)
            vf[dt] = *reinterpret_cast<const short8*>(
                Vb + (size_t)(dt * 16 + lr) * NS + j0 + lg * 8);
    };
    auto bload = [&](int t) -> short8 {
        const int j0 = jq + t * 32;
        return *reinterpret_cast<const short8*>(
            Bb + (size_t)(lane >> 2) * NS + j0 + (lane & 3) * 8);
    };

    auto compute = [&](const short8* kf, const short8* vf, short8 bv) {
        // bias tile -> per-wave LDS (same-wave store->read, single buffer)
        *reinterpret_cast<short8*>(
            &blds[wave][(lane >> 2) * 40 + (lane & 3) * 8]) = bv;
        asm volatile("" ::: "memory");

        f32x4 sc[2];
        #pragma unroll
        for (int s = 0; s < 2; ++s) {
            f32x4 c = (f32x4){0.f, 0.f, 0.f, 0.f};
            c = MFMA(qa[0], kf[s * 2 + 0], c);
            c = MFMA(qa[1], kf[s * 2 + 1], c);
            sc[s] = c;
        }
        #pragma unroll
        for (int s = 0; s < 2; ++s)
            #pragma unroll
            for (int r = 0; r < 4; ++r) {
                const unsigned int u = (unsigned int)(unsigned short)
                    blds[wave][(lg * 4 + r) * 40 + s * 16 + lr] << 16;
                float bb;
                __builtin_memcpy(&bb, &u, 4);
                sc[s][r] = __expf(sc[s][r] * 0.125f + bb);
            }
        den += sc[0] + sc[1];

        #pragma unroll
        for (int s = 0; s < 2; ++s)
            #pragma unroll
            for (int r = 0; r < 4; ++r)
                plds[wave][lg * 4 + r][s * 16 + lr] = f2bf(sc[s][r]);
        asm volatile("" ::: "memory");
        short8 pa = *reinterpret_cast<const short8*>(&plds[wave][lr][lg * 8]);
        asm volatile("" ::: "memory");

        #pragma unroll
        for (int dt = 0; dt < 4; ++dt) ctx[dt] = MFMA(pa, vf[dt], ctx[dt]);
    };

    // prologue: bias 2-deep, K/V 1-deep
    bv0 = bload(0); bv1 = bload(1);
    kvload(0, kfA, vfA);

    // t: use bv[t%3], prefetch bv[(t+2)%3]; kv ping-pong A/B
    bv2 = bload(2); kvload(1, kfB, vfB); compute(kfA, vfA, bv0);   // t=0
    bv0 = bload(3); kvload(2, kfA, vfA); compute(kfB, vfB, bv1);   // t=1
    bv1 = bload(4); kvload(3, kfB, vfB); compute(kfA, vfA, bv2);   // t=2
    bv2 = bload(5); kvload(4, kfA, vfA); compute(kfB, vfB, bv0);   // t=3
    bv0 = bload(6); kvload(5, kfB, vfB); compute(kfA, vfA, bv1);   // t=4
    bv1 = bload(7); kvload(6, kfA, vfA); compute(kfB, vfB, bv2);   // t=5
    kvload(7, kfB, vfB);                 compute(kfA, vfA, bv0);   // t=6
    compute(kfB, vfB, bv1);                                        // t=7

    #pragma unroll
    for (int w = 1; w < 16; w <<= 1) {
        f32x4 o;
        #pragma unroll
        for (int r = 0; r < 4; ++r) o[r] = __shfl_xor(den[r], w, 64);
        den += o;
    }

    #pragma unroll
    for (int dt = 0; dt < 4; ++dt)
        #pragma unroll
        for (int r = 0; r < 4; ++r)
            numlds[wave][lg * 4 + r][dt * 16 + lr] = ctx[dt][r];
    if (lr == 0) {
        #pragma unroll
        for (int r = 0; r < 4; ++r) denlds[wave][lg * 4 + r] = den[r];
    }
    __syncthreads();

    const int ti = threadIdx.x >> 4;
    const int tc = (threadIdx.x & 15) * 4;
    f32x4 n = *reinterpret_cast<const f32x4*>(&numlds[0][ti][tc]);
    n += *reinterpret_cast<const f32x4*>(&numlds[1][ti][tc]);
    n += *reinterpret_cast<const f32x4*>(&numlds[2][ti][tc]);
    n += *reinterpret_cast<const f32x4*>(&numlds[3][ti][tc]);
    const float dd = denlds[0][ti] + denlds[1][ti] + denlds[2][ti] + denlds[3][ti];
    const float inv = 1.0f / dd;
    f32x4 o = n * inv;
    *reinterpret_cast<f32x4*>(out + ((size_t)(b * NS) + i0 + ti) * NHID + h * 64 + tc) = o;
}

extern "C" void kernel_launch(void* const* d_in, const int* in_sizes, int n_in,
                              void* d_out, int out_size, void* d_ws, size_t ws_size,
                              hipStream_t stream) {
    (void)in_sizes; (void)n_in; (void)out_size; (void)ws_size;
    const float* hidden = (const float*)d_in[0];
    const float* bbox   = (const float*)d_in[1];
    const float* mask   = (const float*)d_in[2];
    const float* Wq = (const float*)d_in[3]; const float* bq = (const float*)d_in[4];
    const float* Wk = (const float*)d_in[5]; const float* bk = (const float*)d_in[6];
    const float* Wv = (const float*)d_in[7]; const float* bv = (const float*)d_in[8];
    float* out = (float*)d_out;

    char* ws = (char*)d_ws;
    const size_t qkv_bytes = (size_t)NB * NS * NHID * sizeof(short);   // 3 MB each
    short* Qw  = (short*)ws;
    short* Kw  = (short*)(ws + qkv_bytes);
    short* VTw = (short*)(ws + 2 * qkv_bytes);
    short* biasH = (short*)(ws + 3 * qkv_bytes);                       // 50.3 MB bf16
    const size_t bias_bytes = (size_t)NB * NHEAD * NS * NS * sizeof(short);
    short* Xbf = (short*)(ws + 3 * qkv_bytes + bias_bytes);
    short* Wbf = Xbf + (size_t)2048 * NHID;

    const int cvt_total = (NHE + 3 * WE) / 4;
    cvt_bf16_all<<<cvt_total / 256, 256, 0, stream>>>(hidden, Wq, Wk, Wv, Xbf, Wbf);

    qkv_gemm<<<16 * 36, 256, 0, stream>>>(Xbf, Wbf, bq, bk, bv, Qw, Kw, VTw);

    bias_gemm<<<NS, 256, 0, stream>>>(Qw, bbox, mask, biasH);

    attn2<<<24 * 64, 256, 0, stream>>>(Qw, Kw, VTw, biasH, out);
}

// Round 13
// 215.690 us; speedup vs baseline: 1.0440x; 1.0440x over previous
//
#include <hip/hip_runtime.h>
#include <hip/hip_bf16.h>

typedef short bf4 __attribute__((ext_vector_type(4)));
typedef short short8 __attribute__((ext_vector_type(8)));
typedef float f32x4 __attribute__((ext_vector_type(4)));

#define MFMA(a, b, c) __builtin_amdgcn_mfma_f32_16x16x32_bf16((a), (b), (c), 0, 0, 0)

#define NB 2
#define NS 1024
#define NHID 768
#define NHEAD 12
#define NDH 64

__device__ __forceinline__ short f2bf(float x) {
    __hip_bfloat16 h = __float2bfloat16(x);
    return *reinterpret_cast<short*>(&h);
}

__device__ __forceinline__ int xcd_swz(int orig, int nwg) {
    return (orig & 7) * (nwg >> 3) + (orig >> 3);
}

typedef const __attribute__((address_space(1))) void gas_t;
typedef __attribute__((address_space(3))) void las_t;
__device__ __forceinline__ void gld_lds16(const float* g, float* l) {
    __builtin_amdgcn_global_load_lds((gas_t*)g, (las_t*)l, 16, 0, 0);
}
__device__ __forceinline__ void gld_lds16s(const short* g, short* l) {
    __builtin_amdgcn_global_load_lds((gas_t*)g, (las_t*)l, 16, 0, 0);
}

// ---------------------------------------------------------------------------
// Kernel 0: convert hidden + Wq/Wk/Wv to bf16 (once).
// ---------------------------------------------------------------------------
#define NHE (2048 * 768)
#define WE  (768 * 768)
__global__ void cvt_bf16_all(
    const float* __restrict__ hidden,
    const float* __restrict__ Wq, const float* __restrict__ Wk,
    const float* __restrict__ Wv,
    short* __restrict__ Xbf, short* __restrict__ Wbf)
{
    const int base = (blockIdx.x * 256 + threadIdx.x) * 4;
    const float* src; short* dst; int off;
    if (base < NHE)               { src = hidden; dst = Xbf;          off = base; }
    else if (base < NHE + WE)     { src = Wq;     dst = Wbf;          off = base - NHE; }
    else if (base < NHE + 2 * WE) { src = Wk;     dst = Wbf + WE;     off = base - NHE - WE; }
    else                          { src = Wv;     dst = Wbf + 2 * WE; off = base - NHE - 2 * WE; }
    f32x4 v = *reinterpret_cast<const f32x4*>(src + off);
    bf4 r;
    r[0] = f2bf(v[0]); r[1] = f2bf(v[1]); r[2] = f2bf(v[2]); r[3] = f2bf(v[3]);
    *reinterpret_cast<bf4*>(dst + off) = r;
}

// ---------------------------------------------------------------------------
// Kernel 1: QKV GEMM, LDS-staged + XCD swizzle (R11 version).
// ---------------------------------------------------------------------------
__global__ __launch_bounds__(256, 3) void qkv_gemm(
    const short* __restrict__ Xbf, const short* __restrict__ Wbf,
    const float* __restrict__ bq, const float* __restrict__ bk,
    const float* __restrict__ bv,
    short* __restrict__ Qo, short* __restrict__ Ko, short* __restrict__ VTo)
{
    const int lane = threadIdx.x & 63;
    const int wave = threadIdx.x >> 6;
    const int lg = lane >> 4, lr = lane & 15;

    const int wgid = xcd_swz(blockIdx.x, 16 * 36);
    const int m0 = (wgid / 36) * 128;
    const int n0 = (wgid % 36) * 64;
    const int proj = n0 / NHID;
    const int ncol0 = n0 % NHID;
    const float* bias = proj == 0 ? bq : (proj == 1 ? bk : bv);

    __shared__ short Alds[2][128 * 64];
    __shared__ short Blds[2][64 * 64];

    f32x4 acc[2][4];
    #pragma unroll
    for (int mm = 0; mm < 2; ++mm)
        #pragma unroll
        for (int s = 0; s < 4; ++s) acc[mm][s] = (f32x4){0.f, 0.f, 0.f, 0.f};

    auto stage = [&](int t, int buf) {
        const int k0 = t * 64;
        #pragma unroll
        for (int p = 0; p < 4; ++p) {
            const int op = wave * 4 + p;
            const int unit = op * 64 + lane;
            const int r = unit >> 3, u = unit & 7;
            const int g = u ^ (r & 7);
            gld_lds16s(Xbf + (size_t)(m0 + r) * NHID + k0 + g * 8,
                       &Alds[buf][op * 512]);
        }
        #pragma unroll
        for (int p = 0; p < 2; ++p) {
            const int op = wave * 2 + p;
            const int unit = op * 64 + lane;
            const int r = unit >> 3, u = unit & 7;
            const int g = u ^ (r & 7);
            gld_lds16s(Wbf + (size_t)(n0 + r) * NHID + k0 + g * 8,
                       &Blds[buf][op * 512]);
        }
    };

    auto compute = [&](int buf) {
        #pragma unroll
        for (int kk = 0; kk < 2; ++kk) {
            const int U = kk * 4 + lg;
            short8 a[2];
            #pragma unroll
            for (int mm = 0; mm < 2; ++mm) {
                const int R = wave * 32 + mm * 16 + lr;
                a[mm] = *reinterpret_cast<const short8*>(
                    &Alds[buf][(R * 8 + (U ^ (R & 7))) * 8]);
            }
            #pragma unroll
            for (int s = 0; s < 4; ++s) {
                const int R = s * 16 + lr;
                short8 b = *reinterpret_cast<const short8*>(
                    &Blds[buf][(R * 8 + (U ^ (R & 7))) * 8]);
                acc[0][s] = MFMA(a[0], b, acc[0][s]);
                acc[1][s] = MFMA(a[1], b, acc[1][s]);
            }
        }
    };

    stage(0, 0);
    #pragma unroll 2
    for (int t = 0; t < 12; ++t) {
        const int buf = t & 1;
        asm volatile("s_waitcnt vmcnt(0)" ::: "memory");
        __syncthreads();
        if (t < 11) stage(t + 1, buf ^ 1);
        compute(buf);
    }

    #pragma unroll
    for (int mm = 0; mm < 2; ++mm) {
        #pragma unroll
        for (int s = 0; s < 4; ++s) {
            const int ncol = ncol0 + s * 16 + lr;
            const float badd = bias[ncol];
            #pragma unroll
            for (int r = 0; r < 4; ++r) {
                const int m = m0 + wave * 32 + mm * 16 + lg * 4 + r;
                const short v16 = f2bf(acc[mm][s][r] + badd);
                if (proj == 0) {
                    Qo[(size_t)m * NHID + ncol] = v16;
                } else if (proj == 1) {
                    Ko[(size_t)m * NHID + ncol] = v16;
                } else {
                    const int b = m >> 10, ss = m & 1023;
                    const int h = ncol >> 6, dd = ncol & 63;
                    VTo[(((size_t)(b * NHEAD + h) * NDH + dd) << 10) + ss] = v16;
                }
            }
        }
    }
}

// ---------------------------------------------------------------------------
// Kernel 2: bias GEMM -> bf16, pre-scaled + mask folded (at fetch roofline).
// ---------------------------------------------------------------------------
__global__ __launch_bounds__(256, 2) void bias_gemm(
    const short* __restrict__ Q,
    const float* __restrict__ bbox,
    const float* __restrict__ mask,
    short* __restrict__ biasH)        // (2,12,1024,1024) bf16
{
    const int lane = threadIdx.x & 63;
    const int wave = threadIdx.x >> 6;
    const int lg = lane >> 4, lr = lane & 15;
    const int i = blockIdx.x;
    const int jq = wave * 256;

    __shared__ float lds[4][2][2048];

    short8 qa[2][2];
    #pragma unroll
    for (int b2 = 0; b2 < 2; ++b2)
        #pragma unroll
        for (int kk = 0; kk < 2; ++kk)
            qa[b2][kk] = *reinterpret_cast<const short8*>(
                Q + ((size_t)(b2 * NS) + i) * NHID + lr * 64 + kk * 32 + lg * 8);

    const int r_half = lane >> 5;
    const int u_lin = lane & 31;

    auto stage = [&](int t, int buf) {
        const int j0 = jq + t * 16;
        float* dst = &lds[wave][buf][0];
        #pragma unroll
        for (int w = 0; w < 8; ++w) {
            const int r = 2 * w + r_half;
            const int u = u_lin ^ (r & 7);
            const float* src = bbox + (size_t)(i * NS + j0 + r) * 128 + u * 4;
            gld_lds16(src, dst + w * 256);
        }
    };

    auto compute = [&](int t, int buf) {
        const float* tile = &lds[wave][buf][0];
        const int j0 = jq + t * 16;
        const int x = lr & 7;
        #pragma unroll
        for (int b2 = 0; b2 < 2; ++b2) {
            const float mk = mask[b2 * NS + j0 + lr];
            f32x4 c = (f32x4){0.f, 0.f, 0.f, 0.f};
            #pragma unroll
            for (int kk = 0; kk < 2; ++kk) {
                const int q0 = b2 * 16 + kk * 8 + lg * 2;
                f32x4 ca = *reinterpret_cast<const f32x4*>(tile + (size_t)(lr * 32 + ((q0)     ^ x)) * 4);
                f32x4 cb = *reinterpret_cast<const f32x4*>(tile + (size_t)(lr * 32 + ((q0 + 1) ^ x)) * 4);
                short8 bf;
                bf[0] = f2bf(ca[0]); bf[1] = f2bf(ca[1]); bf[2] = f2bf(ca[2]); bf[3] = f2bf(ca[3]);
                bf[4] = f2bf(cb[0]); bf[5] = f2bf(cb[1]); bf[6] = f2bf(cb[2]); bf[7] = f2bf(cb[3]);
                c = MFMA(qa[b2][kk], bf, c);
            }
            if (lg < 3) {
                #pragma unroll
                for (int r = 0; r < 4; ++r) {
                    const int n = lg * 4 + r;
                    biasH[((size_t)(b2 * NHEAD + n) * NS + i) * NS + j0 + lr] =
                        f2bf(c[r] * 0.125f + mk);
                }
            }
        }
    };

    stage(0, 0);
    for (int t = 0; t < 16; ++t) {
        const int buf = t & 1;
        asm volatile("s_waitcnt lgkmcnt(0)" ::: "memory");
        if (t < 15) stage(t + 1, buf ^ 1);
        if (t == 0 || t == 15) asm volatile("s_waitcnt vmcnt(8)"  ::: "memory");
        else                   asm volatile("s_waitcnt vmcnt(16)" ::: "memory");
        compute(t, buf);
    }
}

// ---------------------------------------------------------------------------
// Kernel 3 (NEW): attn3 — LDS-staged attention.
// Block = (b,h, 64-row i-chunk); grid 384, XCD-swizzled. 4 waves x 16 i-rows.
// All waves share K/V j-tiles (staged once per block); bias per-wave tile.
// Double-buffered gld_lds16 staging (3 ops/thread/tile), vmcnt(0)+barrier.
// No cross-wave combine: each wave covers full j for its rows.
// ---------------------------------------------------------------------------
__global__ __launch_bounds__(256, 3) void attn3(
    const short* __restrict__ Q,
    const short* __restrict__ K,
    const short* __restrict__ VT,
    const short* __restrict__ biasH,
    float* __restrict__ out)
{
    const int tid = threadIdx.x;
    const int lane = tid & 63;
    const int wave = tid >> 6;
    const int lg = lane >> 4, lr = lane & 15;

    const int wgid = xcd_swz(blockIdx.x, 24 * 16);
    const int bh = wgid >> 4;             // 48/XCD = 2 full (b,h) groups
    const int ic = wgid & 15;
    const int b = bh / NHEAD, h = bh % NHEAD;
    const int i0 = ic * 64 + wave * 16;   // this wave's 16 rows

    __shared__ short Klds[2][2048];       // 32 j-rows x 8 units (XOR-swz)
    __shared__ short Vlds[2][2048];       // 64 dh-rows x 4 units (XOR-swz)
    __shared__ short Blds[2][2048];       // 4 waves x 16 rows x 32 j
    __shared__ short plds[4][16 * 40];

    short8 qa[2];
    #pragma unroll
    for (int kk = 0; kk < 2; ++kk)
        qa[kk] = *reinterpret_cast<const short8*>(
            Q + ((size_t)(b * NS) + i0 + lr) * NHID + h * 64 + kk * 32 + lg * 8);

    const short* Kb = K + (size_t)b * NS * NHID + h * 64;
    const short* Vb = VT + (size_t)(b * NHEAD + h) * NDH * NS;
    const short* Bb = biasH + ((size_t)(b * NHEAD + h) * NS + ic * 64) * NS;

    f32x4 ctx[4];
    #pragma unroll
    for (int dt = 0; dt < 4; ++dt) ctx[dt] = (f32x4){0.f, 0.f, 0.f, 0.f};
    f32x4 den = (f32x4){0.f, 0.f, 0.f, 0.f};

    // per-thread staging coords (constant across tiles)
    const int kr = tid >> 3, ku = tid & 7;           // K: 32 rows x 8 units
    const int kgu = ku ^ (kr & 7);
    const int vr = tid >> 2, vu = tid & 3;           // V: 64 rows x 4 units
    const int vgu = vu ^ (vr & 3);
    const int br = tid >> 2, bu = tid & 3;           // bias: 64 rows x 4 units

    auto stage = [&](int t, int buf) {
        const int j0 = t * 32;
        gld_lds16s(Kb + (size_t)(j0 + kr) * NHID + kgu * 8, &Klds[buf][tid * 8]);
        gld_lds16s(Vb + (size_t)vr * NS + j0 + vgu * 8,     &Vlds[buf][tid * 8]);
        gld_lds16s(Bb + (size_t)br * NS + j0 + bu * 8,      &Blds[buf][tid * 8]);
    };

    auto compute = [&](int buf) {
        // QK^T
        f32x4 sc[2];
        #pragma unroll
        for (int s = 0; s < 2; ++s) {
            f32x4 c = (f32x4){0.f, 0.f, 0.f, 0.f};
            #pragma unroll
            for (int kk = 0; kk < 2; ++kk) {
                const int R = s * 16 + lr;
                const int U = kk * 4 + lg;
                short8 kf = *reinterpret_cast<const short8*>(
                    &Klds[buf][(R * 8 + (U ^ (R & 7))) * 8]);
                c = MFMA(qa[kk], kf, c);
            }
            sc[s] = c;
        }
        // bias + exp  (bias' = raw*0.125 + mask, bf16)
        #pragma unroll
        for (int s = 0; s < 2; ++s)
            #pragma unroll
            for (int r = 0; r < 4; ++r) {
                const unsigned int u = (unsigned int)(unsigned short)
                    Blds[buf][wave * 512 + (lg * 4 + r) * 32 + s * 16 + lr] << 16;
                float bb;
                __builtin_memcpy(&bb, &u, 4);
                sc[s][r] = __expf(sc[s][r] * 0.125f + bb);
            }
        den += sc[0] + sc[1];

        // P -> bf16 transpose via per-wave LDS
        #pragma unroll
        for (int s = 0; s < 2; ++s)
            #pragma unroll
            for (int r = 0; r < 4; ++r)
                plds[wave][(lg * 4 + r) * 40 + s * 16 + lr] = f2bf(sc[s][r]);
        asm volatile("" ::: "memory");
        short8 pa = *reinterpret_cast<const short8*>(&plds[wave][lr * 40 + lg * 8]);
        asm volatile("" ::: "memory");

        // PV
        #pragma unroll
        for (int dt = 0; dt < 4; ++dt) {
            const int R = dt * 16 + lr;
            short8 vf = *reinterpret_cast<const short8*>(
                &Vlds[buf][(R * 4 + (lg ^ (R & 3))) * 8]);
            ctx[dt] = MFMA(pa, vf, ctx[dt]);
        }
    };

    stage(0, 0);
    for (int t = 0; t < 32; ++t) {
        const int buf = t & 1;
        asm volatile("s_waitcnt vmcnt(0)" ::: "memory");
        __syncthreads();
        if (t < 31) stage(t + 1, buf ^ 1);
        compute(buf);
    }

    // reduce den over the 16 j-lanes (lr)
    #pragma unroll
    for (int w = 1; w < 16; w <<= 1) {
        f32x4 o;
        #pragma unroll
        for (int r = 0; r < 4; ++r) o[r] = __shfl_xor(den[r], w, 64);
        den += o;
    }

    // direct store: wave owns rows exclusively
    #pragma unroll
    for (int r = 0; r < 4; ++r) {
        const float inv = 1.0f / den[r];
        const int i = i0 + lg * 4 + r;
        #pragma unroll
        for (int dt = 0; dt < 4; ++dt)
            out[((size_t)(b * NS) + i) * NHID + h * 64 + dt * 16 + lr] =
                ctx[dt][r] * inv;
    }
}

extern "C" void kernel_launch(void* const* d_in, const int* in_sizes, int n_in,
                              void* d_out, int out_size, void* d_ws, size_t ws_size,
                              hipStream_t stream) {
    (void)in_sizes; (void)n_in; (void)out_size; (void)ws_size;
    const float* hidden = (const float*)d_in[0];
    const float* bbox   = (const float*)d_in[1];
    const float* mask   = (const float*)d_in[2];
    const float* Wq = (const float*)d_in[3]; const float* bq = (const float*)d_in[4];
    const float* Wk = (const float*)d_in[5]; const float* bk = (const float*)d_in[6];
    const float* Wv = (const float*)d_in[7]; const float* bv = (const float*)d_in[8];
    float* out = (float*)d_out;

    char* ws = (char*)d_ws;
    const size_t qkv_bytes = (size_t)NB * NS * NHID * sizeof(short);   // 3 MB each
    short* Qw  = (short*)ws;
    short* Kw  = (short*)(ws + qkv_bytes);
    short* VTw = (short*)(ws + 2 * qkv_bytes);
    short* biasH = (short*)(ws + 3 * qkv_bytes);                       // 50.3 MB bf16
    const size_t bias_bytes = (size_t)NB * NHEAD * NS * NS * sizeof(short);
    short* Xbf = (short*)(ws + 3 * qkv_bytes + bias_bytes);
    short* Wbf = Xbf + (size_t)2048 * NHID;

    const int cvt_total = (NHE + 3 * WE) / 4;
    cvt_bf16_all<<<cvt_total / 256, 256, 0, stream>>>(hidden, Wq, Wk, Wv, Xbf, Wbf);

    qkv_gemm<<<16 * 36, 256, 0, stream>>>(Xbf, Wbf, bq, bk, bv, Qw, Kw, VTw);

    bias_gemm<<<NS, 256, 0, stream>>>(Qw, bbox, mask, biasH);

    attn3<<<24 * 16, 256, 0, stream>>>(Qw, Kw, VTw, biasH, out);
}